// Round 2
// baseline (437.709 us; speedup 1.0000x reference)
//
#include <hip/hip_runtime.h>
#include <hip/hip_bf16.h>
#include <math.h>

// Problem constants
#define NROWS 8192
#define INDIM 64
#define CONDD 32
#define K0DIM 96
#define HDIM  256
#define ODIM  64

// Jacobian GEMM config: M=8192, N=64, K=65536 (hk), chunk=64, split-K=8
#define SPLITS 8
#define MTILE  128
#define NCHUNKS 1024            // 65536 / 64
#define CHUNKS_PER_WG (NCHUNKS / SPLITS)  // 128
#define APAD 72                 // padded row length (bf16 elems) for LDS tiles

typedef __bf16 bf16x8 __attribute__((ext_vector_type(8)));
typedef float  f32x4  __attribute__((ext_vector_type(4)));

__device__ __forceinline__ float bf2f(unsigned short u) {
    unsigned int v = ((unsigned int)u) << 16;
    float f;
    __builtin_memcpy(&f, &v, 4);
    return f;
}

__device__ __forceinline__ unsigned short f2bf(float f) {
    unsigned int u;
    __builtin_memcpy(&u, &f, 4);
    unsigned int r = (u + 0x7fffu + ((u >> 16) & 1u)) >> 16;  // RNE
    return (unsigned short)r;
}

// ---------------------------------------------------------------------------
// K1: fused forward MLP (vector f32). 256 wgs x 256 thr, 32 rows per wg.
// Produces out1 (f32), hp0 (bf16 [8192][256]), hp1 (bf16 [8192][256]).
// ---------------------------------------------------------------------------
__global__ __launch_bounds__(256) void k_fwd(
    const float* __restrict__ eps, const float* __restrict__ xc,
    const float* __restrict__ W0, const float* __restrict__ b0,
    const float* __restrict__ W1, const float* __restrict__ b1,
    const float* __restrict__ W2, const float* __restrict__ b2,
    const float* __restrict__ betap,
    unsigned short* __restrict__ hp0g, unsigned short* __restrict__ hp1g,
    float* __restrict__ out1)
{
    __shared__ float inpL[32 * 96];
    __shared__ float act0[32 * 256];
    __shared__ float act1[32 * 256];

    const int t  = threadIdx.x;
    const int n0 = blockIdx.x * 32;
    const float beta = betap[0];
    const float inv11 = 1.0f / 1.1f;

    // stage concat(eps, x) rows into LDS (f32)
    for (int idx = t; idx < 32 * 96; idx += 256) {
        int r = idx / 96, c = idx - r * 96;
        float v = (c < 64) ? eps[(size_t)(n0 + r) * 64 + c]
                           : xc[(size_t)(n0 + r) * 32 + (c - 64)];
        inpL[idx] = v;
    }
    __syncthreads();

    // ---- layer 0: h0 = inp @ W0^T + b0 ----
    {
        const int j = t;  // neuron 0..255
        float acc[32];
#pragma unroll
        for (int r = 0; r < 32; r++) acc[r] = 0.f;
        for (int cb = 0; cb < 12; cb++) {
            const float4 w0 = *(const float4*)(W0 + j * 96 + cb * 8);
            const float4 w1 = *(const float4*)(W0 + j * 96 + cb * 8 + 4);
#pragma unroll
            for (int r = 0; r < 32; r++) {
                const float4 x0 = *(const float4*)(inpL + r * 96 + cb * 8);
                const float4 x1 = *(const float4*)(inpL + r * 96 + cb * 8 + 4);
                acc[r] += w0.x * x0.x + w0.y * x0.y + w0.z * x0.z + w0.w * x0.w
                        + w1.x * x1.x + w1.y * x1.y + w1.z * x1.z + w1.w * x1.w;
            }
        }
        const float bj = b0[j];
#pragma unroll
        for (int r = 0; r < 32; r++) {
            float h = acc[r] + bj;
            float s = 1.f / (1.f + __expf(-beta * h));
            float f = h * s * inv11;
            float hp = beta * f + s * (inv11 - beta * f);
            act0[r * 256 + j] = f;
            hp0g[(size_t)(n0 + r) * 256 + j] = f2bf(hp);
        }
    }
    __syncthreads();

    // ---- layer 1: h1 = a0 @ W1^T + b1 ----
    {
        const int j = t;
        float acc[32];
#pragma unroll
        for (int r = 0; r < 32; r++) acc[r] = 0.f;
        for (int cb = 0; cb < 32; cb++) {
            const float4 w0 = *(const float4*)(W1 + j * 256 + cb * 8);
            const float4 w1 = *(const float4*)(W1 + j * 256 + cb * 8 + 4);
#pragma unroll
            for (int r = 0; r < 32; r++) {
                const float4 x0 = *(const float4*)(act0 + r * 256 + cb * 8);
                const float4 x1 = *(const float4*)(act0 + r * 256 + cb * 8 + 4);
                acc[r] += w0.x * x0.x + w0.y * x0.y + w0.z * x0.z + w0.w * x0.w
                        + w1.x * x1.x + w1.y * x1.y + w1.z * x1.z + w1.w * x1.w;
            }
        }
        const float bj = b1[j];
#pragma unroll
        for (int r = 0; r < 32; r++) {
            float h = acc[r] + bj;
            float s = 1.f / (1.f + __expf(-beta * h));
            float f = h * s * inv11;
            float hp = beta * f + s * (inv11 - beta * f);
            act1[r * 256 + j] = f;
            hp1g[(size_t)(n0 + r) * 256 + j] = f2bf(hp);
        }
    }
    __syncthreads();

    // ---- layer 2: g = a1 @ W2^T + b2; out1 = f32(eps + g) ----
    {
        const int j  = t & 63;
        const int rb = t >> 6;  // 0..3, wave-uniform
        float acc[8];
#pragma unroll
        for (int rr = 0; rr < 8; rr++) acc[rr] = 0.f;
        for (int cb = 0; cb < 32; cb++) {
            const float4 w0 = *(const float4*)(W2 + j * 256 + cb * 8);
            const float4 w1 = *(const float4*)(W2 + j * 256 + cb * 8 + 4);
#pragma unroll
            for (int rr = 0; rr < 8; rr++) {
                const int r = rb * 8 + rr;
                const float4 x0 = *(const float4*)(act1 + r * 256 + cb * 8);
                const float4 x1 = *(const float4*)(act1 + r * 256 + cb * 8 + 4);
                acc[rr] += w0.x * x0.x + w0.y * x0.y + w0.z * x0.z + w0.w * x0.w
                         + w1.x * x1.x + w1.y * x1.y + w1.z * x1.z + w1.w * x1.w;
            }
        }
        const float bj = b2[j];
#pragma unroll
        for (int rr = 0; rr < 8; rr++) {
            const int r = rb * 8 + rr;
            float g = acc[rr] + bj;
            out1[(size_t)(n0 + r) * 64 + j] = eps[(size_t)(n0 + r) * 64 + j] + g;
        }
    }
}

// ---------------------------------------------------------------------------
// K2: precompute B tensor, chunk-transposed:
// Bpre[c][d][kk] = W2[d,h] * W1[h,k] * W0[k,d],  c=hk-chunk (h=c/4, k=(c%4)*64+kk)
// 8 MB bf16. 256 wgs x 256 thr (4 chunks per wg, thread=(c_loc,d)).
// ---------------------------------------------------------------------------
__global__ __launch_bounds__(256) void k_bpre(
    const float* __restrict__ W0, const float* __restrict__ W1,
    const float* __restrict__ W2, unsigned short* __restrict__ Bpre)
{
    const int t = threadIdx.x;
    const int cloc = t >> 6;  // 0..3
    const int d = t & 63;
    const int c = blockIdx.x * 4 + cloc;
    const int h = c >> 2;
    const int k0 = (c & 3) << 6;
    const float w2 = W2[d * 256 + h];
    unsigned short* dst = Bpre + ((size_t)c * 64 + d) * 64;
#pragma unroll
    for (int kk8 = 0; kk8 < 8; kk8++) {
        unsigned int pk[4];
#pragma unroll
        for (int p = 0; p < 4; p++) {
            int k_lo = k0 + kk8 * 8 + 2 * p;
            float vlo = w2 * W1[h * 256 + k_lo] * W0[k_lo * 96 + d];
            float vhi = w2 * W1[h * 256 + k_lo + 1] * W0[(k_lo + 1) * 96 + d];
            pk[p] = (unsigned int)f2bf(vlo) | ((unsigned int)f2bf(vhi) << 16);
        }
        *(uint4*)(dst + kk8 * 8) = make_uint4(pk[0], pk[1], pk[2], pk[3]);
    }
}

// ---------------------------------------------------------------------------
// K3: Jacobian-diagonal GEMM. diag = A(8192x65536) @ B(65536x64), split-K=8.
// A generated on the fly: A[n, 64c+kk] = hp1[n, c/4] * hp0[n, (c%4)*64+kk].
// wg = 256 thr (4 waves, 2x2 over 128x64 tile), mfma 16x16x32 bf16.
// ---------------------------------------------------------------------------
__global__ __launch_bounds__(256) void k_jac(
    const unsigned short* __restrict__ hp0g,
    const unsigned short* __restrict__ hp1g,
    const unsigned short* __restrict__ Bpre,
    float* __restrict__ part)
{
    __shared__ __align__(16) unsigned short Alds[MTILE * APAD];
    __shared__ __align__(16) unsigned short Blds[64 * APAD];

    const int t = threadIdx.x;
    const int bx = blockIdx.x;
    const int mt = bx & 63;   // m-tile 0..63
    const int s  = bx >> 6;   // split 0..7
    const int n0 = mt * MTILE;

    const int lane = t & 63;
    const int wid  = t >> 6;       // 0..3
    const int wm = wid >> 1;       // 0..1 (m)
    const int wn = wid & 1;        // 0..1 (n)
    const int l15 = lane & 15;
    const int lg  = lane >> 4;     // 0..3

    f32x4 acc[4][2];
#pragma unroll
    for (int mf = 0; mf < 4; mf++)
#pragma unroll
        for (int nf = 0; nf < 2; nf++)
            acc[mf][nf] = (f32x4){0.f, 0.f, 0.f, 0.f};

    const int arow = t >> 3;   // 0..31 base row for A-gen
    const int akk8 = t & 7;    // 16B column slot

    for (int ci = 0; ci < CHUNKS_PER_WG; ci++) {
        const int c  = s * CHUNKS_PER_WG + ci;
        const int h  = c >> 2;
        const int k0 = (c & 3) << 6;

        // --- generate A chunk: 128 rows x 64 cols (bf16) ---
#pragma unroll
        for (int i = 0; i < 4; i++) {
            const int row = i * 32 + arow;
            const int n = n0 + row;
            const uint4 v = *(const uint4*)(hp0g + (size_t)n * 256 + k0 + akk8 * 8);
            const float f1 = bf2f(hp1g[(size_t)n * 256 + h]);
            unsigned int o[4];
#pragma unroll
            for (int e = 0; e < 4; e++) {
                unsigned int w = ((const unsigned int*)&v)[e];
                float lo = bf2f((unsigned short)(w & 0xffffu)) * f1;
                float hi = bf2f((unsigned short)(w >> 16)) * f1;
                o[e] = (unsigned int)f2bf(lo) | ((unsigned int)f2bf(hi) << 16);
            }
            *(uint4*)(Alds + row * APAD + akk8 * 8) = make_uint4(o[0], o[1], o[2], o[3]);
        }
        // --- stage B chunk transposed: Blds[d][kk], 64x64 ---
#pragma unroll
        for (int i = 0; i < 2; i++) {
            const int slot = i * 256 + t;
            const int d = slot >> 3, kk8 = slot & 7;
            const uint4 v = *(const uint4*)(Bpre + ((size_t)c * 64 + d) * 64 + kk8 * 8);
            *(uint4*)(Blds + d * APAD + kk8 * 8) = v;
        }
        __syncthreads();

        // --- MFMA: 2 k-steps of 32 ---
#pragma unroll
        for (int ks = 0; ks < 2; ks++) {
            bf16x8 bfr[2];
#pragma unroll
            for (int nf = 0; nf < 2; nf++)
                bfr[nf] = *(const bf16x8*)(Blds + (wn * 32 + nf * 16 + l15) * APAD + ks * 32 + lg * 8);
#pragma unroll
            for (int mf = 0; mf < 4; mf++) {
                bf16x8 afr = *(const bf16x8*)(Alds + (wm * 64 + mf * 16 + l15) * APAD + ks * 32 + lg * 8);
                acc[mf][0] = __builtin_amdgcn_mfma_f32_16x16x32_bf16(afr, bfr[0], acc[mf][0], 0, 0, 0);
                acc[mf][1] = __builtin_amdgcn_mfma_f32_16x16x32_bf16(afr, bfr[1], acc[mf][1], 0, 0, 0);
            }
        }
        __syncthreads();
    }

    // --- store partials: part[s][n][d] ---
    float* pw = part + (size_t)s * NROWS * 64;
#pragma unroll
    for (int mf = 0; mf < 4; mf++)
#pragma unroll
        for (int nf = 0; nf < 2; nf++)
#pragma unroll
            for (int e = 0; e < 4; e++) {
                const int n = n0 + wm * 64 + mf * 16 + lg * 4 + e;
                const int d = wn * 32 + nf * 16 + l15;
                pw[(size_t)n * 64 + d] = acc[mf][nf][e];
            }
}

// ---------------------------------------------------------------------------
// K4: finalize j[n] = sum_d log|1 + sum_s part[s][n][d]|. One wave per row.
// ---------------------------------------------------------------------------
__global__ __launch_bounds__(256) void k_fin(
    const float* __restrict__ part, float* __restrict__ outj)
{
    const int t = threadIdx.x;
    const int wavei = t >> 6, lane = t & 63;
    const int n = blockIdx.x * 4 + wavei;
    float ssum = 0.f;
#pragma unroll
    for (int s = 0; s < SPLITS; s++)
        ssum += part[((size_t)s * NROWS + n) * 64 + lane];
    float v = logf(fabsf(1.0f + ssum));
#pragma unroll
    for (int m = 1; m < 64; m <<= 1) v += __shfl_xor(v, m, 64);
    if (lane == 0) outj[n] = v;
}

// ---------------------------------------------------------------------------
extern "C" void kernel_launch(void* const* d_in, const int* in_sizes, int n_in,
                              void* d_out, int out_size, void* d_ws, size_t ws_size,
                              hipStream_t stream)
{
    const float* eps  = (const float*)d_in[0];
    const float* xc   = (const float*)d_in[1];
    const float* W0   = (const float*)d_in[2];
    const float* b0   = (const float*)d_in[3];
    const float* W1   = (const float*)d_in[4];
    const float* b1   = (const float*)d_in[5];
    const float* W2   = (const float*)d_in[6];
    const float* b2   = (const float*)d_in[7];
    const float* beta = (const float*)d_in[8];

    float* out1 = (float*)d_out;                       // 8192*64 f32
    float* outj = out1 + (size_t)NROWS * 64;           // 8192 f32

    char* ws = (char*)d_ws;
    unsigned short* hp0  = (unsigned short*)(ws);                              // 4 MB
    unsigned short* hp1  = (unsigned short*)(ws + (size_t)4  * 1024 * 1024);   // 4 MB
    unsigned short* Bpre = (unsigned short*)(ws + (size_t)8  * 1024 * 1024);   // 8 MB
    float*          part = (float*)        (ws + (size_t)16 * 1024 * 1024);    // 16 MB

    hipLaunchKernelGGL(k_bpre, dim3(256), dim3(256), 0, stream, W0, W1, W2, Bpre);
    hipLaunchKernelGGL(k_fwd, dim3(256), dim3(256), 0, stream,
                       eps, xc, W0, b0, W1, b1, W2, b2, beta, hp0, hp1, out1);
    hipLaunchKernelGGL(k_jac, dim3(64 * SPLITS), dim3(256), 0, stream, hp0, hp1, Bpre, part);
    hipLaunchKernelGGL(k_fin, dim3(NROWS / 4), dim3(256), 0, stream, part, outj);
}

// Round 4
// 353.515 us; speedup vs baseline: 1.2382x; 1.2382x over previous
//
#include <hip/hip_runtime.h>
#include <hip/hip_bf16.h>
#include <math.h>

// Problem constants
#define NROWS 8192
#define INDIM 64
#define CONDD 32
#define K0DIM 96
#define HDIM  256
#define ODIM  64

// Jacobian GEMM config: M=8192, N=64, K=65536 (hk), chunk=64, split-K=16
#define SPLITS 16
#define MTILE  128
#define NCHUNKS 1024                      // 65536 / 64
#define CHUNKS_PER_WG (NCHUNKS / SPLITS)  // 64

typedef __bf16 bf16x8 __attribute__((ext_vector_type(8)));
typedef float  f32x4  __attribute__((ext_vector_type(4)));

__device__ __forceinline__ float bf2f(unsigned short u) {
    unsigned int v = ((unsigned int)u) << 16;
    float f;
    __builtin_memcpy(&f, &v, 4);
    return f;
}

__device__ __forceinline__ unsigned short f2bf(float f) {
    unsigned int u;
    __builtin_memcpy(&u, &f, 4);
    unsigned int r = (u + 0x7fffu + ((u >> 16) & 1u)) >> 16;  // RNE
    return (unsigned short)r;
}

__device__ __forceinline__ float asf(unsigned int u) {
    float f; __builtin_memcpy(&f, &u, 4); return f;
}

// ---------------------------------------------------------------------------
// K1: fused forward MLP (vector f32). 256 wgs x 256 thr, 32 rows per wg.
// Produces out1 (f32), hp0 (bf16 [8192][256]), hp1 (bf16 [8192][256]).
// ---------------------------------------------------------------------------
__global__ __launch_bounds__(256) void k_fwd(
    const float* __restrict__ eps, const float* __restrict__ xc,
    const float* __restrict__ W0, const float* __restrict__ b0,
    const float* __restrict__ W1, const float* __restrict__ b1,
    const float* __restrict__ W2, const float* __restrict__ b2,
    const float* __restrict__ betap,
    unsigned short* __restrict__ hp0g, unsigned short* __restrict__ hp1g,
    float* __restrict__ out1)
{
    __shared__ float inpL[32 * 96];
    __shared__ float act0[32 * 256];
    __shared__ float act1[32 * 256];

    const int t  = threadIdx.x;
    const int n0 = blockIdx.x * 32;
    const float beta = betap[0];
    const float inv11 = 1.0f / 1.1f;

    for (int idx = t; idx < 32 * 96; idx += 256) {
        int r = idx / 96, c = idx - r * 96;
        float v = (c < 64) ? eps[(size_t)(n0 + r) * 64 + c]
                           : xc[(size_t)(n0 + r) * 32 + (c - 64)];
        inpL[idx] = v;
    }
    __syncthreads();

    // ---- layer 0 ----
    {
        const int j = t;
        float acc[32];
#pragma unroll
        for (int r = 0; r < 32; r++) acc[r] = 0.f;
        for (int cb = 0; cb < 12; cb++) {
            const float4 w0 = *(const float4*)(W0 + j * 96 + cb * 8);
            const float4 w1 = *(const float4*)(W0 + j * 96 + cb * 8 + 4);
#pragma unroll
            for (int r = 0; r < 32; r++) {
                const float4 x0 = *(const float4*)(inpL + r * 96 + cb * 8);
                const float4 x1 = *(const float4*)(inpL + r * 96 + cb * 8 + 4);
                acc[r] += w0.x * x0.x + w0.y * x0.y + w0.z * x0.z + w0.w * x0.w
                        + w1.x * x1.x + w1.y * x1.y + w1.z * x1.z + w1.w * x1.w;
            }
        }
        const float bj = b0[j];
#pragma unroll
        for (int r = 0; r < 32; r++) {
            float h = acc[r] + bj;
            float s = 1.f / (1.f + __expf(-beta * h));
            float f = h * s * inv11;
            float hp = beta * f + s * (inv11 - beta * f);
            act0[r * 256 + j] = f;
            hp0g[(size_t)(n0 + r) * 256 + j] = f2bf(hp);
        }
    }
    __syncthreads();

    // ---- layer 1 ----
    {
        const int j = t;
        float acc[32];
#pragma unroll
        for (int r = 0; r < 32; r++) acc[r] = 0.f;
        for (int cb = 0; cb < 32; cb++) {
            const float4 w0 = *(const float4*)(W1 + j * 256 + cb * 8);
            const float4 w1 = *(const float4*)(W1 + j * 256 + cb * 8 + 4);
#pragma unroll
            for (int r = 0; r < 32; r++) {
                const float4 x0 = *(const float4*)(act0 + r * 256 + cb * 8);
                const float4 x1 = *(const float4*)(act0 + r * 256 + cb * 8 + 4);
                acc[r] += w0.x * x0.x + w0.y * x0.y + w0.z * x0.z + w0.w * x0.w
                        + w1.x * x1.x + w1.y * x1.y + w1.z * x1.z + w1.w * x1.w;
            }
        }
        const float bj = b1[j];
#pragma unroll
        for (int r = 0; r < 32; r++) {
            float h = acc[r] + bj;
            float s = 1.f / (1.f + __expf(-beta * h));
            float f = h * s * inv11;
            float hp = beta * f + s * (inv11 - beta * f);
            act1[r * 256 + j] = f;
            hp1g[(size_t)(n0 + r) * 256 + j] = f2bf(hp);
        }
    }
    __syncthreads();

    // ---- layer 2 ----
    {
        const int j  = t & 63;
        const int rb = t >> 6;
        float acc[8];
#pragma unroll
        for (int rr = 0; rr < 8; rr++) acc[rr] = 0.f;
        for (int cb = 0; cb < 32; cb++) {
            const float4 w0 = *(const float4*)(W2 + j * 256 + cb * 8);
            const float4 w1 = *(const float4*)(W2 + j * 256 + cb * 8 + 4);
#pragma unroll
            for (int rr = 0; rr < 8; rr++) {
                const int r = rb * 8 + rr;
                const float4 x0 = *(const float4*)(act1 + r * 256 + cb * 8);
                const float4 x1 = *(const float4*)(act1 + r * 256 + cb * 8 + 4);
                acc[rr] += w0.x * x0.x + w0.y * x0.y + w0.z * x0.z + w0.w * x0.w
                         + w1.x * x1.x + w1.y * x1.y + w1.z * x1.z + w1.w * x1.w;
            }
        }
        const float bj = b2[j];
#pragma unroll
        for (int rr = 0; rr < 8; rr++) {
            const int r = rb * 8 + rr;
            out1[(size_t)(n0 + r) * 64 + j] = eps[(size_t)(n0 + r) * 64 + j] + acc[rr] + bj;
        }
    }
}

// ---------------------------------------------------------------------------
// K2: precompute B tensor (chunk-transposed) + zero the jd accumulator.
// Bpre[c][d][kk] = W2[d,h]*W1[h,k]*W0[k,d], c = 4h + (k>>6), kk = k&63.
// ---------------------------------------------------------------------------
__global__ __launch_bounds__(256) void k_bpre(
    const float* __restrict__ W0, const float* __restrict__ W1,
    const float* __restrict__ W2, unsigned short* __restrict__ Bpre,
    float* __restrict__ jd)
{
    const int t = threadIdx.x;
    // zero jd: 256 wgs * 256 thr * 8 floats = 524288
    {
        const int gid = blockIdx.x * 256 + t;
        float4 z = make_float4(0.f, 0.f, 0.f, 0.f);
        ((float4*)jd)[gid * 2]     = z;
        ((float4*)jd)[gid * 2 + 1] = z;
    }
    const int cloc = t >> 6;
    const int d = t & 63;
    const int c = blockIdx.x * 4 + cloc;
    const int h = c >> 2;
    const int k0 = (c & 3) << 6;
    const float w2 = W2[d * 256 + h];
    unsigned short* dst = Bpre + ((size_t)c * 64 + d) * 64;
#pragma unroll
    for (int kk8 = 0; kk8 < 8; kk8++) {
        unsigned int pk[4];
#pragma unroll
        for (int p = 0; p < 4; p++) {
            int k_lo = k0 + kk8 * 8 + 2 * p;
            float vlo = w2 * W1[h * 256 + k_lo] * W0[k_lo * 96 + d];
            float vhi = w2 * W1[h * 256 + k_lo + 1] * W0[(k_lo + 1) * 96 + d];
            pk[p] = (unsigned int)f2bf(vlo) | ((unsigned int)f2bf(vhi) << 16);
        }
        *(uint4*)(dst + kk8 * 8) = make_uint4(pk[0], pk[1], pk[2], pk[3]);
    }
}

// ---------------------------------------------------------------------------
// K3: Jacobian-diagonal GEMM, split-K=16, atomicAdd epilogue into jd.
// LDS: stride 64 shorts (128B rows), XOR swizzle byte^=((row&7)<<4) —
// conflict-free-minimal for both b128 writes and 16-row-stride frag reads.
// Next-chunk global loads issued right after barrier-1 (hide under MFMA).
// ---------------------------------------------------------------------------
__global__ __launch_bounds__(256) void k_jac(
    const unsigned short* __restrict__ hp0g,
    const unsigned short* __restrict__ hp1g,
    const unsigned short* __restrict__ Bpre,
    float* __restrict__ jd)
{
    __shared__ __align__(16) unsigned short Alds[MTILE * 64];
    __shared__ __align__(16) unsigned short Blds[64 * 64];

    const int t = threadIdx.x;
    const int bx = blockIdx.x;
    const int mt = bx & 63;   // m-tile 0..63
    const int s  = bx >> 6;   // split 0..15
    const int n0 = mt * MTILE;

    const int lane = t & 63;
    const int wid  = t >> 6;
    const int wm = wid >> 1;
    const int wn = wid & 1;
    const int l15 = lane & 15;
    const int lg  = lane >> 4;

    f32x4 acc[4][2];
#pragma unroll
    for (int mf = 0; mf < 4; mf++)
#pragma unroll
        for (int nf = 0; nf < 2; nf++)
            acc[mf][nf] = (f32x4){0.f, 0.f, 0.f, 0.f};

    const int arow = t >> 3;   // 0..31
    const int akk8 = t & 7;    // 16B col slot
    const int bd   = t >> 3;   // 0..31 (B row base)

    uint4 pa[4]; unsigned short pf1[4]; uint4 pb[2];

#define LOADC(cc)                                                              \
    {                                                                          \
        const int c_ = (cc);                                                   \
        const int h_ = c_ >> 2, k0_ = (c_ & 3) << 6;                           \
        _Pragma("unroll")                                                      \
        for (int i = 0; i < 4; i++) {                                          \
            const int n_ = n0 + i * 32 + arow;                                 \
            pa[i]  = *(const uint4*)(hp0g + (size_t)n_ * 256 + k0_ + akk8 * 8);\
            pf1[i] = hp1g[(size_t)n_ * 256 + h_];                              \
        }                                                                      \
        _Pragma("unroll")                                                      \
        for (int i = 0; i < 2; i++) {                                          \
            const int d_ = i * 32 + bd;                                        \
            pb[i] = *(const uint4*)(Bpre + ((size_t)c_ * 64 + d_) * 64 + akk8 * 8); \
        }                                                                      \
    }

    LOADC(s * CHUNKS_PER_WG);

#pragma unroll 1
    for (int ci = 0; ci < CHUNKS_PER_WG; ci++) {
        // --- stage A (gen: hp1-scale in f32, pack via v_cvt_pk_bf16_f32) ---
#pragma unroll
        for (int i = 0; i < 4; i++) {
            const int row = i * 32 + arow;
            const float f1 = bf2f(pf1[i]);
            unsigned int o[4];
#pragma unroll
            for (int e = 0; e < 4; e++) {
                const unsigned int w = ((const unsigned int*)&pa[i])[e];
                const float lo = asf(w << 16) * f1;
                const float hi = asf(w & 0xffff0000u) * f1;
                unsigned int pk;
                asm("v_cvt_pk_bf16_f32 %0, %1, %2" : "=v"(pk) : "v"(lo), "v"(hi));
                o[e] = pk;
            }
            const int cb = (akk8 * 16) ^ ((row & 7) << 4);
            *(uint4*)((char*)Alds + row * 128 + cb) = make_uint4(o[0], o[1], o[2], o[3]);
        }
        // --- stage B ---
#pragma unroll
        for (int i = 0; i < 2; i++) {
            const int d = i * 32 + bd;
            const int cb = (akk8 * 16) ^ ((d & 7) << 4);
            *(uint4*)((char*)Blds + d * 128 + cb) = pb[i];
        }
        __syncthreads();

        // --- prefetch next chunk (latency hides under MFMA) ---
        if (ci < CHUNKS_PER_WG - 1) LOADC(s * CHUNKS_PER_WG + ci + 1);

        // --- MFMA: 2 k-steps of 32 ---
#pragma unroll
        for (int ks = 0; ks < 2; ks++) {
            bf16x8 bfr[2];
#pragma unroll
            for (int nf = 0; nf < 2; nf++) {
                const int row = wn * 32 + nf * 16 + l15;
                const int cb = (ks * 64 + lg * 16) ^ ((row & 7) << 4);
                bfr[nf] = *(const bf16x8*)((char*)Blds + row * 128 + cb);
            }
#pragma unroll
            for (int mf = 0; mf < 4; mf++) {
                const int row = wm * 64 + mf * 16 + l15;
                const int cb = (ks * 64 + lg * 16) ^ ((row & 7) << 4);
                const bf16x8 afr = *(const bf16x8*)((char*)Alds + row * 128 + cb);
                acc[mf][0] = __builtin_amdgcn_mfma_f32_16x16x32_bf16(afr, bfr[0], acc[mf][0], 0, 0, 0);
                acc[mf][1] = __builtin_amdgcn_mfma_f32_16x16x32_bf16(afr, bfr[1], acc[mf][1], 0, 0, 0);
            }
        }
        __syncthreads();
    }
#undef LOADC

    // --- epilogue: atomic split accumulation into jd[n][d] ---
#pragma unroll
    for (int mf = 0; mf < 4; mf++)
#pragma unroll
        for (int nf = 0; nf < 2; nf++)
#pragma unroll
            for (int e = 0; e < 4; e++) {
                const int n = n0 + wm * 64 + mf * 16 + lg * 4 + e;
                const int d = wn * 32 + nf * 16 + l15;
                atomicAdd(&jd[(size_t)n * 64 + d], acc[mf][nf][e]);
            }
}

// ---------------------------------------------------------------------------
// K4: finalize j[n] = sum_d log|1 + jd[n,d]|. One wave per row.
// ---------------------------------------------------------------------------
__global__ __launch_bounds__(256) void k_fin(
    const float* __restrict__ jd, float* __restrict__ outj)
{
    const int t = threadIdx.x;
    const int wavei = t >> 6, lane = t & 63;
    const int n = blockIdx.x * 4 + wavei;
    float v = logf(fabsf(1.0f + jd[(size_t)n * 64 + lane]));
#pragma unroll
    for (int m = 1; m < 64; m <<= 1) v += __shfl_xor(v, m, 64);
    if (lane == 0) outj[n] = v;
}

// ---------------------------------------------------------------------------
extern "C" void kernel_launch(void* const* d_in, const int* in_sizes, int n_in,
                              void* d_out, int out_size, void* d_ws, size_t ws_size,
                              hipStream_t stream)
{
    const float* eps  = (const float*)d_in[0];
    const float* xc   = (const float*)d_in[1];
    const float* W0   = (const float*)d_in[2];
    const float* b0   = (const float*)d_in[3];
    const float* W1   = (const float*)d_in[4];
    const float* b1   = (const float*)d_in[5];
    const float* W2   = (const float*)d_in[6];
    const float* b2   = (const float*)d_in[7];
    const float* beta = (const float*)d_in[8];

    float* out1 = (float*)d_out;                       // 8192*64 f32
    float* outj = out1 + (size_t)NROWS * 64;           // 8192 f32

    char* ws = (char*)d_ws;
    unsigned short* hp0  = (unsigned short*)(ws);                              // 4 MB
    unsigned short* hp1  = (unsigned short*)(ws + (size_t)4  * 1024 * 1024);   // 4 MB
    unsigned short* Bpre = (unsigned short*)(ws + (size_t)8  * 1024 * 1024);   // 8 MB
    float*          jd   = (float*)        (ws + (size_t)16 * 1024 * 1024);    // 2 MB

    hipLaunchKernelGGL(k_bpre, dim3(256), dim3(256), 0, stream, W0, W1, W2, Bpre, jd);
    hipLaunchKernelGGL(k_fwd, dim3(256), dim3(256), 0, stream,
                       eps, xc, W0, b0, W1, b1, W2, b2, beta, hp0, hp1, out1);
    hipLaunchKernelGGL(k_jac, dim3(64 * SPLITS), dim3(256), 0, stream, hp0, hp1, Bpre, jd);
    hipLaunchKernelGGL(k_fin, dim3(NROWS / 4), dim3(256), 0, stream, jd, outj);
}

// Round 5
// 340.586 us; speedup vs baseline: 1.2852x; 1.0380x over previous
//
#include <hip/hip_runtime.h>
#include <hip/hip_bf16.h>
#include <math.h>

// Problem constants
#define NROWS 8192

// Jacobian config: loop over h (256), K=256 contraction per h, split h 4 ways
#define SPLITH 4
#define HPER   64       // 256 / SPLITH
#define MTILE  128

typedef __bf16 bf16x8 __attribute__((ext_vector_type(8)));
typedef float  f32x4  __attribute__((ext_vector_type(4)));

__device__ __forceinline__ float bf2f(unsigned short u) {
    unsigned int v = ((unsigned int)u) << 16;
    float f;
    __builtin_memcpy(&f, &v, 4);
    return f;
}

__device__ __forceinline__ unsigned short f2bf(float f) {
    unsigned int u;
    __builtin_memcpy(&u, &f, 4);
    unsigned int r = (u + 0x7fffu + ((u >> 16) & 1u)) >> 16;  // RNE
    return (unsigned short)r;
}

// ---------------------------------------------------------------------------
// K1: fused forward MLP (vector f32). 256 wgs x 256 thr, 32 rows per wg.
// Produces out1 (f32), hp0 (bf16 [8192][256]), hp1T (bf16 [256 h][8192 n]).
// ---------------------------------------------------------------------------
__global__ __launch_bounds__(256) void k_fwd(
    const float* __restrict__ eps, const float* __restrict__ xc,
    const float* __restrict__ W0, const float* __restrict__ b0,
    const float* __restrict__ W1, const float* __restrict__ b1,
    const float* __restrict__ W2, const float* __restrict__ b2,
    const float* __restrict__ betap,
    unsigned short* __restrict__ hp0g, unsigned short* __restrict__ hp1Tg,
    float* __restrict__ out1)
{
    __shared__ float inpL[32 * 96];
    __shared__ float act0[32 * 256];
    __shared__ float act1[32 * 256];

    const int t  = threadIdx.x;
    const int n0 = blockIdx.x * 32;
    const float beta = betap[0];
    const float inv11 = 1.0f / 1.1f;

    for (int idx = t; idx < 32 * 96; idx += 256) {
        int r = idx / 96, c = idx - r * 96;
        float v = (c < 64) ? eps[(size_t)(n0 + r) * 64 + c]
                           : xc[(size_t)(n0 + r) * 32 + (c - 64)];
        inpL[idx] = v;
    }
    __syncthreads();

    // ---- layer 0 ----
    {
        const int j = t;
        float acc[32];
#pragma unroll
        for (int r = 0; r < 32; r++) acc[r] = 0.f;
        for (int cb = 0; cb < 12; cb++) {
            const float4 w0 = *(const float4*)(W0 + j * 96 + cb * 8);
            const float4 w1 = *(const float4*)(W0 + j * 96 + cb * 8 + 4);
#pragma unroll
            for (int r = 0; r < 32; r++) {
                const float4 x0 = *(const float4*)(inpL + r * 96 + cb * 8);
                const float4 x1 = *(const float4*)(inpL + r * 96 + cb * 8 + 4);
                acc[r] += w0.x * x0.x + w0.y * x0.y + w0.z * x0.z + w0.w * x0.w
                        + w1.x * x1.x + w1.y * x1.y + w1.z * x1.z + w1.w * x1.w;
            }
        }
        const float bj = b0[j];
#pragma unroll
        for (int r = 0; r < 32; r++) {
            float h = acc[r] + bj;
            float s = 1.f / (1.f + __expf(-beta * h));
            float f = h * s * inv11;
            float hp = beta * f + s * (inv11 - beta * f);
            act0[r * 256 + j] = f;
            hp0g[(size_t)(n0 + r) * 256 + j] = f2bf(hp);
        }
    }
    __syncthreads();

    // ---- layer 1 ----
    {
        const int j = t;
        float acc[32];
#pragma unroll
        for (int r = 0; r < 32; r++) acc[r] = 0.f;
        for (int cb = 0; cb < 32; cb++) {
            const float4 w0 = *(const float4*)(W1 + j * 256 + cb * 8);
            const float4 w1 = *(const float4*)(W1 + j * 256 + cb * 8 + 4);
#pragma unroll
            for (int r = 0; r < 32; r++) {
                const float4 x0 = *(const float4*)(act0 + r * 256 + cb * 8);
                const float4 x1 = *(const float4*)(act0 + r * 256 + cb * 8 + 4);
                acc[r] += w0.x * x0.x + w0.y * x0.y + w0.z * x0.z + w0.w * x0.w
                        + w1.x * x1.x + w1.y * x1.y + w1.z * x1.z + w1.w * x1.w;
            }
        }
        const float bj = b1[j];
#pragma unroll
        for (int r = 0; r < 32; r++) {
            float h = acc[r] + bj;
            float s = 1.f / (1.f + __expf(-beta * h));
            float f = h * s * inv11;
            float hp = beta * f + s * (inv11 - beta * f);
            act1[r * 256 + j] = f;
            // transposed store: hp1T[h=j][n]
            hp1Tg[(size_t)j * NROWS + n0 + r] = f2bf(hp);
        }
    }
    __syncthreads();

    // ---- layer 2 ----
    {
        const int j  = t & 63;
        const int rb = t >> 6;
        float acc[8];
#pragma unroll
        for (int rr = 0; rr < 8; rr++) acc[rr] = 0.f;
        for (int cb = 0; cb < 32; cb++) {
            const float4 w0 = *(const float4*)(W2 + j * 256 + cb * 8);
            const float4 w1 = *(const float4*)(W2 + j * 256 + cb * 8 + 4);
#pragma unroll
            for (int rr = 0; rr < 8; rr++) {
                const int r = rb * 8 + rr;
                const float4 x0 = *(const float4*)(act1 + r * 256 + cb * 8);
                const float4 x1 = *(const float4*)(act1 + r * 256 + cb * 8 + 4);
                acc[rr] += w0.x * x0.x + w0.y * x0.y + w0.z * x0.z + w0.w * x0.w
                         + w1.x * x1.x + w1.y * x1.y + w1.z * x1.z + w1.w * x1.w;
            }
        }
        const float bj = b2[j];
#pragma unroll
        for (int rr = 0; rr < 8; rr++) {
            const int r = rb * 8 + rr;
            out1[(size_t)(n0 + r) * 64 + j] = eps[(size_t)(n0 + r) * 64 + j] + acc[rr] + bj;
        }
    }
}

// ---------------------------------------------------------------------------
// K2: precompute B panels, PRE-SWIZZLED so a linear 32KB copy into LDS yields
// the XOR-swizzled layout the MFMA fragment reads expect.
// Logical: Bh[h][d][k] = W2[d,h]*W1[h,k]*W0[k,d]  (d<64, k<256)
// Byte pos within panel: (d*512 + k*2) ^ ((d&7)<<4).  One h-panel per wg.
// ---------------------------------------------------------------------------
__global__ __launch_bounds__(256) void k_bpre(
    const float* __restrict__ W0, const float* __restrict__ W1,
    const float* __restrict__ W2, unsigned char* __restrict__ Bpre)
{
    const int t = threadIdx.x;
    const int h = blockIdx.x;
    const int d = t >> 2;          // 0..63
    const int kq = t & 3;          // k-quarter
    const float w2 = W2[d * 256 + h];
    unsigned char* pan = Bpre + (size_t)h * 32768;
#pragma unroll
    for (int u = 0; u < 8; u++) {
        const int k0 = kq * 64 + u * 8;
        unsigned int pk[4];
#pragma unroll
        for (int p = 0; p < 4; p++) {
            const int kl = k0 + 2 * p;
            float vlo = w2 * W1[h * 256 + kl]     * W0[kl * 96 + d];
            float vhi = w2 * W1[h * 256 + kl + 1] * W0[(kl + 1) * 96 + d];
            pk[p] = (unsigned int)f2bf(vlo) | ((unsigned int)f2bf(vhi) << 16);
        }
        const int cb = (d * 512 + k0 * 2) ^ ((d & 7) << 4);
        *(uint4*)(pan + cb) = make_uint4(pk[0], pk[1], pk[2], pk[3]);
    }
}

// ---------------------------------------------------------------------------
// K3: Jacobian diagonal, h-loop formulation.
//   P_h[n,d] = sum_k hp0[n,k] * Bh[k,d]   (one K=256 MFMA pass)
//   acc[n,d] += bf2f(hp1[n,h]) * P_h[n,d] (f32 scale on accumulators)
// A-frags (hp0) live in registers for the whole h-loop. B panels double-
// buffered in LDS, reg-staged with loads issued before the compute phase.
// grid = 64 m-tiles x 4 h-splits = 256 wgs, 1 wg/CU (128 KB LDS).
// ---------------------------------------------------------------------------
__global__ __launch_bounds__(256, 1) void k_jac(
    const unsigned short* __restrict__ hp0g,
    const unsigned short* __restrict__ hp1Tg,
    const unsigned char* __restrict__ Bpre,
    float* __restrict__ part)
{
    // [0,65536): phase1 hp0 tile (swizzled); phase2 first 16KB = hp1T [64][128]
    // [65536,131072): B panel double buffer (2 x 32KB)
    __shared__ __align__(16) unsigned char lds[131072];

    const int t  = threadIdx.x;
    const int bx = blockIdx.x;
    const int mt = bx & 63;        // m-tile
    const int sp = bx >> 6;        // h-split 0..3
    const int n0 = mt * MTILE;
    const int h0 = sp * HPER;

    const int lane = t & 63;
    const int wid  = t >> 6;
    const int wm = wid >> 1;       // 0..1 (m)
    const int wn = wid & 1;        // 0..1 (n)
    const int l15 = lane & 15;
    const int lg  = lane >> 4;

    // ---- phase 1: stage hp0 tile swizzled ----
#pragma unroll
    for (int i = 0; i < 16; i++) {
        const int u = i * 256 + t;          // 4096 16B-units
        const int row = u >> 5, cu = u & 31;
        const uint4 v = *(const uint4*)(hp0g + (size_t)(n0 + row) * 256 + cu * 8);
        const int cb = (cu * 16) ^ ((row & 7) << 4);
        *(uint4*)(lds + row * 512 + cb) = v;
    }
    __syncthreads();

    // issue prologue global loads early (B panel h0, hp1T tile)
    uint4 pb[8];
    const uint4* Bp4 = (const uint4*)Bpre;
#pragma unroll
    for (int i = 0; i < 8; i++)
        pb[i] = Bp4[(size_t)h0 * 2048 + i * 256 + t];
    uint4 hv[4];
#pragma unroll
    for (int i = 0; i < 4; i++) {
        const int u = i * 256 + t;          // 1024 units: hi = u>>4, c8 = u&15
        hv[i] = *(const uint4*)(hp1Tg + (size_t)(h0 + (u >> 4)) * NROWS + n0 + (u & 15) * 8);
    }

    // extract A-frags into registers (reused across all 64 h)
    bf16x8 afr[4][8];
#pragma unroll
    for (int mf = 0; mf < 4; mf++)
#pragma unroll
        for (int ks = 0; ks < 8; ks++) {
            const int row = wm * 64 + mf * 16 + l15;
            const int cb = (ks * 64 + lg * 16) ^ ((row & 7) << 4);
            afr[mf][ks] = *(const bf16x8*)(lds + row * 512 + cb);
        }
    __syncthreads();   // region A free now

    // write hp1T tile + B panel h0 into LDS
#pragma unroll
    for (int i = 0; i < 4; i++) {
        const int u = i * 256 + t;
        *(uint4*)(lds + (u >> 4) * 256 + (u & 15) * 16) = hv[i];
    }
#pragma unroll
    for (int i = 0; i < 8; i++)
        *(uint4*)(lds + 65536 + i * 4096 + t * 16) = pb[i];
    __syncthreads();

    f32x4 acc[4][2];
#pragma unroll
    for (int mf = 0; mf < 4; mf++)
#pragma unroll
        for (int nf = 0; nf < 2; nf++)
            acc[mf][nf] = (f32x4){0.f, 0.f, 0.f, 0.f};

#define COMPUTE_H(hi_)                                                          \
    {                                                                           \
        const unsigned char* buf = lds + 65536 + ((hi_) & 1) * 32768;           \
        f32x4 P[4][2];                                                          \
        _Pragma("unroll")                                                       \
        for (int mf = 0; mf < 4; mf++) {                                        \
            P[mf][0] = (f32x4){0.f, 0.f, 0.f, 0.f};                             \
            P[mf][1] = (f32x4){0.f, 0.f, 0.f, 0.f};                             \
        }                                                                       \
        _Pragma("unroll")                                                       \
        for (int ks = 0; ks < 8; ks++) {                                        \
            bf16x8 bfr[2];                                                      \
            _Pragma("unroll")                                                   \
            for (int nf = 0; nf < 2; nf++) {                                    \
                const int dd = wn * 32 + nf * 16 + l15;                         \
                const int cb = (ks * 64 + lg * 16) ^ ((dd & 7) << 4);           \
                bfr[nf] = *(const bf16x8*)(buf + dd * 512 + cb);                \
            }                                                                   \
            _Pragma("unroll")                                                   \
            for (int mf = 0; mf < 4; mf++) {                                    \
                P[mf][0] = __builtin_amdgcn_mfma_f32_16x16x32_bf16(             \
                    afr[mf][ks], bfr[0], P[mf][0], 0, 0, 0);                    \
                P[mf][1] = __builtin_amdgcn_mfma_f32_16x16x32_bf16(             \
                    afr[mf][ks], bfr[1], P[mf][1], 0, 0, 0);                    \
            }                                                                   \
        }                                                                       \
        _Pragma("unroll")                                                       \
        for (int mf = 0; mf < 4; mf++) {                                        \
            const ushort4 sc = *(const ushort4*)(                               \
                lds + (hi_) * 256 + (wm * 64 + mf * 16 + lg * 4) * 2);          \
            const float s0 = bf2f(sc.x), s1 = bf2f(sc.y);                       \
            const float s2 = bf2f(sc.z), s3 = bf2f(sc.w);                       \
            acc[mf][0][0] += s0 * P[mf][0][0]; acc[mf][1][0] += s0 * P[mf][1][0];\
            acc[mf][0][1] += s1 * P[mf][0][1]; acc[mf][1][1] += s1 * P[mf][1][1];\
            acc[mf][0][2] += s2 * P[mf][0][2]; acc[mf][1][2] += s2 * P[mf][1][2];\
            acc[mf][0][3] += s3 * P[mf][0][3]; acc[mf][1][3] += s3 * P[mf][1][3];\
        }                                                                       \
    }

#pragma unroll 1
    for (int hi = 0; hi < HPER - 1; hi++) {
        // issue next panel's loads (latency hides under MFMA below)
#pragma unroll
        for (int i = 0; i < 8; i++)
            pb[i] = Bp4[(size_t)(h0 + hi + 1) * 2048 + i * 256 + t];
        COMPUTE_H(hi);
        __syncthreads();
        // write next panel into the other buffer
        {
            unsigned char* nb = lds + 65536 + ((hi + 1) & 1) * 32768;
#pragma unroll
            for (int i = 0; i < 8; i++)
                *(uint4*)(nb + i * 4096 + t * 16) = pb[i];
        }
        __syncthreads();
    }
    COMPUTE_H(HPER - 1);
#undef COMPUTE_H

    // ---- epilogue: plain stores into part[sp][n][d] ----
    float* pw = part + (size_t)sp * NROWS * 64;
#pragma unroll
    for (int mf = 0; mf < 4; mf++)
#pragma unroll
        for (int nf = 0; nf < 2; nf++)
#pragma unroll
            for (int e = 0; e < 4; e++) {
                const int n = n0 + wm * 64 + mf * 16 + lg * 4 + e;
                const int d = wn * 32 + nf * 16 + l15;
                pw[(size_t)n * 64 + d] = acc[mf][nf][e];
            }
}

// ---------------------------------------------------------------------------
// K4: finalize j[n] = sum_d log|1 + sum_sp part[sp][n][d]|. One wave per row.
// ---------------------------------------------------------------------------
__global__ __launch_bounds__(256) void k_fin(
    const float* __restrict__ part, float* __restrict__ outj)
{
    const int t = threadIdx.x;
    const int wavei = t >> 6, lane = t & 63;
    const int n = blockIdx.x * 4 + wavei;
    float ssum = 0.f;
#pragma unroll
    for (int s = 0; s < SPLITH; s++)
        ssum += part[((size_t)s * NROWS + n) * 64 + lane];
    float v = logf(fabsf(1.0f + ssum));
#pragma unroll
    for (int m = 1; m < 64; m <<= 1) v += __shfl_xor(v, m, 64);
    if (lane == 0) outj[n] = v;
}

// ---------------------------------------------------------------------------
extern "C" void kernel_launch(void* const* d_in, const int* in_sizes, int n_in,
                              void* d_out, int out_size, void* d_ws, size_t ws_size,
                              hipStream_t stream)
{
    const float* eps  = (const float*)d_in[0];
    const float* xc   = (const float*)d_in[1];
    const float* W0   = (const float*)d_in[2];
    const float* b0   = (const float*)d_in[3];
    const float* W1   = (const float*)d_in[4];
    const float* b1   = (const float*)d_in[5];
    const float* W2   = (const float*)d_in[6];
    const float* b2   = (const float*)d_in[7];
    const float* beta = (const float*)d_in[8];

    float* out1 = (float*)d_out;                       // 8192*64 f32
    float* outj = out1 + (size_t)NROWS * 64;           // 8192 f32

    char* ws = (char*)d_ws;
    unsigned short* hp0   = (unsigned short*)(ws);                              // 4 MB
    unsigned short* hp1T  = (unsigned short*)(ws + (size_t)4  * 1024 * 1024);   // 4 MB
    unsigned char*  Bpre  = (unsigned char*) (ws + (size_t)8  * 1024 * 1024);   // 8 MB
    float*          part  = (float*)         (ws + (size_t)16 * 1024 * 1024);   // 8 MB (4 x 2MB)

    hipLaunchKernelGGL(k_bpre, dim3(256), dim3(256), 0, stream, W0, W1, W2, Bpre);
    hipLaunchKernelGGL(k_fwd, dim3(256), dim3(256), 0, stream,
                       eps, xc, W0, b0, W1, b1, W2, b2, beta, hp0, hp1T, out1);
    hipLaunchKernelGGL(k_jac, dim3(64 * SPLITH), dim3(256), 0, stream, hp0, hp1T, Bpre, part);
    hipLaunchKernelGGL(k_fin, dim3(NROWS / 4), dim3(256), 0, stream, part, outj);
}